// Round 2
// baseline (305.103 us; speedup 1.0000x reference)
//
#include <hip/hip_runtime.h>
#include <hip/hip_bf16.h>
#include <math.h>

// Problem constants (B,F,H,E,O) = (512,512,512,8,512)
enum { Bq = 512, Fq = 512, Hq = 512, Eq = 8, Oq = 512, NBLK = 512 };

typedef __attribute__((ext_vector_type(8))) short short8;
typedef __attribute__((ext_vector_type(4))) float floatx4;

static __device__ __forceinline__ unsigned short f2bf(float f) {
  unsigned u = __float_as_uint(f);
  u += 0x7fffu + ((u >> 16) & 1u);
  return (unsigned short)(u >> 16);
}
static __device__ __forceinline__ float bf2f(unsigned short h) {
  return __uint_as_float(((unsigned)h) << 16);
}
static __device__ __forceinline__ float elu1(float v) {
  return v > 0.f ? v : (__expf(v) - 1.f);
}

// async global->LDS 16B copy (wave-uniform LDS base + lane*16 scatter)
typedef __attribute__((address_space(1))) const unsigned int gu32;
typedef __attribute__((address_space(3))) unsigned int lu32;
static __device__ __forceinline__ void gld16(const unsigned short* g,
                                             unsigned short* l) {
  __builtin_amdgcn_global_load_lds((gu32*)g, (lu32*)l, 16, 0, 0);
}

// XOR swizzle on 16B chunks (fragment-read conflicts -> 2-way = free).
static __device__ __forceinline__ int swz(int q, int r) {
  return (q & ~7) | ((q ^ r) & 7);
}

// one 256-thread block converts 256 float4 (1024 elems) fp32->bf16
static __device__ __forceinline__ void cvt_chunk(const float* __restrict__ src,
                                                 unsigned short* __restrict__ dst,
                                                 int chunk, int tid) {
  int j = chunk * 256 + tid;
  float4 v = ((const float4*)src)[j];
  ushort4 o;
  o.x = f2bf(v.x); o.y = f2bf(v.y); o.z = f2bf(v.z); o.w = f2bf(v.w);
  *(ushort4*)(dst + 4 * (size_t)j) = o;
}

// load 8 fp32 -> bf16x8
static __device__ __forceinline__ short8 cvt8(const float* __restrict__ p) {
  float4 v0 = *(const float4*)p, v1 = *(const float4*)(p + 4);
  short8 o;
  o[0] = (short)f2bf(v0.x); o[1] = (short)f2bf(v0.y);
  o[2] = (short)f2bf(v0.z); o[3] = (short)f2bf(v0.w);
  o[4] = (short)f2bf(v1.x); o[5] = (short)f2bf(v1.y);
  o[6] = (short)f2bf(v1.z); o[7] = (short)f2bf(v1.w);
  return o;
}

// --- device-scope global barrier (single-use counter per sync) --------------
// release-add, spin-acquire; bounded spin converts any co-residency surprise
// into a finite (wrong-answer) run instead of a hang. With
// __launch_bounds__(256,2) + 48 KB LDS, 2 blocks/CU x 256 CUs = all 512
// blocks co-resident, so the bound never triggers in practice.
static __device__ __forceinline__ void gsync(unsigned* bar) {
  __syncthreads();
  if (threadIdx.x == 0) {
    __hip_atomic_fetch_add(bar, 1u, __ATOMIC_RELEASE,
                           __HIP_MEMORY_SCOPE_AGENT);
    unsigned tries = 0;
    while (__hip_atomic_load(bar, __ATOMIC_RELAXED,
                             __HIP_MEMORY_SCOPE_AGENT) < (unsigned)NBLK) {
      __builtin_amdgcn_s_sleep(4);
      if (++tries > (1u << 22)) break;  // ~0.5 s escape hatch
    }
    __builtin_amdgcn_fence(__ATOMIC_ACQUIRE, "agent");
  }
  __syncthreads();
}

// --- gating GEMM tile (blocks 0..255 of a phase) ----------------------------
// 32x32 tile, BK=256 x 2 k-steps, 32 KB LDS (As 16 KB + Ws 16 KB).
// W always VALU-staged from fp32; A either fp32-cvt (F32A) or bf16 gld16.
template <int F32A>
static __device__ void gating_tile(int blk, int tid, unsigned short* As,
                                   unsigned short* Ws,
                                   const unsigned short* __restrict__ A,
                                   const float* __restrict__ Af,
                                   const float* __restrict__ Wf,
                                   const float* __restrict__ bias,
                                   unsigned short* __restrict__ C) {
  const int wave = tid >> 6, lane = tid & 63;
  const int wm = wave >> 1, wn = wave & 1;
  const int lr = lane & 15, lk = lane >> 4;
  const int m0 = (blk >> 4) * 32, n0 = (blk & 15) * 32;
  const int rA = wm * 16 + lr, rB = wn * 16 + lr;
  floatx4 ac[4];
#pragma unroll
  for (int j = 0; j < 4; j++) ac[j] = (floatx4){0.f, 0.f, 0.f, 0.f};
#pragma unroll
  for (int kk = 0; kk < 2; kk++) {
    const int kb = kk * 256;
    if (kk) __syncthreads();  // previous step's LDS reads done before restage
#pragma unroll
    for (int i = 0; i < 4; i++) {
      int c = tid + i * 256;
      int r = c >> 5, q = c & 31;
      if (F32A) {
        *(short8*)&As[(r * 32 + swz(q, r)) * 8] =
            cvt8(Af + (size_t)(m0 + r) * 512 + kb + q * 8);
      } else {
        gld16(&A[(size_t)(m0 + r) * 512 + kb + swz(q, r) * 8],
              &As[(c & ~63) * 8]);
      }
    }
#pragma unroll
    for (int i = 0; i < 4; i++) {
      int c = tid + i * 256;
      int r = c >> 5, q = c & 31;
      *(short8*)&Ws[(r * 32 + swz(q, r)) * 8] =
          cvt8(Wf + (size_t)(n0 + r) * 512 + kb + q * 8);
    }
    __syncthreads();
#pragma unroll
    for (int s = 0; s < 8; s++) {
      int q = s * 4 + lk;
      short8 av = *(const short8*)&As[rA * 256 + swz(q, rA) * 8];
      short8 bv = *(const short8*)&Ws[rB * 256 + swz(q, rB) * 8];
      ac[s & 3] =
          __builtin_amdgcn_mfma_f32_16x16x32_bf16(av, bv, ac[s & 3], 0, 0, 0);
    }
  }
  floatx4 acc = (ac[0] + ac[1]) + (ac[2] + ac[3]);
  int n = n0 + wn * 16 + lr;
  float bn = bias[n];
  // C/D layout (m89-verified): col = lane&15, row = (lane>>4)*4 + reg
#pragma unroll
  for (int r = 0; r < 4; r++) {
    int m = m0 + wm * 16 + lk * 4 + r;
    C[(size_t)m * 512 + n] = f2bf(elu1(acc[r] + bn));
  }
}

// --- gate softmax: 4 samples per block (blocks 0..127 of phase C) -----------
static __device__ void gate_softmax(int blk, int tid,
                                    const unsigned short* __restrict__ G1,
                                    const float* __restrict__ gw2,
                                    const float* __restrict__ gb2,
                                    float* __restrict__ g) {
  const int wave = tid >> 6, lane = tid & 63;
  const int b = blk * 4 + wave;
  float xv[8];
#pragma unroll
  for (int t = 0; t < 8; t++) xv[t] = bf2f(G1[(size_t)b * Hq + t * 64 + lane]);
  float le[Eq];
#pragma unroll
  for (int e = 0; e < Eq; e++) {
    float p = 0.f;
#pragma unroll
    for (int t = 0; t < 8; t++)
      p += xv[t] * gw2[(size_t)e * Hq + t * 64 + lane];
#pragma unroll
    for (int o = 32; o > 0; o >>= 1) p += __shfl_xor(p, o);
    le[e] = p + gb2[e];
  }
  float m = le[0];
#pragma unroll
  for (int e = 1; e < Eq; e++) m = fmaxf(m, le[e]);
  float s = 0.f;
#pragma unroll
  for (int e = 0; e < Eq; e++) {
    le[e] = __expf(le[e] - m);
    s += le[e];
  }
  float inv = 1.f / s;
  if (lane == 0) {
#pragma unroll
    for (int e = 0; e < Eq; e++) g[(size_t)b * Eq + e] = le[e] * inv;
  }
}

// ---- expert GEMM phase: 32x32 tile, 8 experts/block, dbuf W, A-frag hoist --
// all 512 blocks participate: blk -> (n0, m0, kz) = 16 x 16 x 2. 48 KB LDS.
template <int FROMX, int FROMP, int ATOMIC>
static __device__ void expert_phase(int blk, int tid, unsigned short* sm,
                                    const float* __restrict__ Xf,
                                    const float* __restrict__ Pin,
                                    const unsigned short* __restrict__ Wb,
                                    const float* __restrict__ g,
                                    const float* __restrict__ beta,
                                    float* __restrict__ Pout) {
  unsigned short* As = sm;                                 // 16 KB (32x256)
  unsigned short* const Wsb[2] = {sm + 8192, sm + 16384};  // 2 x 16 KB
  const int wave = tid >> 6, lane = tid & 63;
  const int wm = wave >> 1, wn = wave & 1;
  const int lr = lane & 15, lk = lane >> 4;
  const int n0 = (blk & 15) * 32;
  const int m0 = ((blk >> 4) & 15) * 32;
  const int kz = blk >> 8, kbeg = kz * 256;

  // stage A panel (32x256): 1024 chunks, 4 per thread
  if (FROMP) {
#pragma unroll
    for (int i = 0; i < 4; i++) {
      int c = tid + i * 256;
      int r = c >> 5, q = c & 31;
      const float* p0 = Pin + (size_t)(m0 + r) * 512 + kbeg + q * 8;
      const float* p1 = p0 + (size_t)Bq * Hq;
      float4 x0 = *(const float4*)p0, x1 = *(const float4*)(p0 + 4);
      float4 y0 = *(const float4*)p1, y1 = *(const float4*)(p1 + 4);
      short8 o;
      o[0] = (short)f2bf(elu1(x0.x + y0.x));
      o[1] = (short)f2bf(elu1(x0.y + y0.y));
      o[2] = (short)f2bf(elu1(x0.z + y0.z));
      o[3] = (short)f2bf(elu1(x0.w + y0.w));
      o[4] = (short)f2bf(elu1(x1.x + y1.x));
      o[5] = (short)f2bf(elu1(x1.y + y1.y));
      o[6] = (short)f2bf(elu1(x1.z + y1.z));
      o[7] = (short)f2bf(elu1(x1.w + y1.w));
      *(short8*)&As[(r * 32 + swz(q, r)) * 8] = o;
    }
  } else if (FROMX) {
#pragma unroll
    for (int i = 0; i < 4; i++) {
      int c = tid + i * 256;
      int r = c >> 5, q = c & 31;
      *(short8*)&As[(r * 32 + swz(q, r)) * 8] =
          cvt8(Xf + (size_t)(m0 + r) * 512 + kbeg + q * 8);
    }
  }
  // stage W panel for expert e into buffer b
  auto stageW = [&](int e, int b) {
    const unsigned short* Wp = Wb + ((size_t)e * 512 + n0) * 512 + kbeg;
    unsigned short* W = Wsb[b];
#pragma unroll
    for (int i = 0; i < 4; i++) {
      int c = tid + i * 256;
      int r = c >> 5, ql = c & 31;
      gld16(&Wp[(size_t)r * 512 + swz(ql, r) * 8], &W[(c & ~63) * 8]);
    }
  };
  stageW(0, 0);
  // gates for this lane's 4 output rows
  float g8[4][8];
#pragma unroll
  for (int r = 0; r < 4; r++) {
    int m = m0 + wm * 16 + lk * 4 + r;
    float4 ga = *(const float4*)&g[(size_t)m * 8];
    float4 gb = *(const float4*)&g[(size_t)m * 8 + 4];
    g8[r][0] = ga.x; g8[r][1] = ga.y; g8[r][2] = ga.z; g8[r][3] = ga.w;
    g8[r][4] = gb.x; g8[r][5] = gb.y; g8[r][6] = gb.z; g8[r][7] = gb.w;
  }

  const int rA = wm * 16 + lr, rB = wn * 16 + lr;
  short8 af[8];  // A fragments, hoisted once at e==0 (invariant over experts)
  floatx4 fin = {0.f, 0.f, 0.f, 0.f};
#pragma unroll
  for (int e = 0; e < 8; e++) {
    __syncthreads();                        // A + W[e] ready; fences reuse
    if (e < 7) stageW(e + 1, (e + 1) & 1);  // prefetch overlaps MFMA
    if (e == 0) {
#pragma unroll
      for (int s = 0; s < 8; s++)
        af[s] = *(const short8*)&As[rA * 256 + swz(s * 4 + lk, rA) * 8];
    }
    const unsigned short* wb = Wsb[e & 1];
    floatx4 c0 = {0.f, 0.f, 0.f, 0.f}, c1 = {0.f, 0.f, 0.f, 0.f};
#pragma unroll
    for (int s = 0; s < 8; s++) {
      short8 bv = *(const short8*)&wb[rB * 256 + swz(s * 4 + lk, rB) * 8];
      if (s & 1)
        c1 = __builtin_amdgcn_mfma_f32_16x16x32_bf16(af[s], bv, c1, 0, 0, 0);
      else
        c0 = __builtin_amdgcn_mfma_f32_16x16x32_bf16(af[s], bv, c0, 0, 0, 0);
    }
    floatx4 ae = c0 + c1;
#pragma unroll
    for (int r = 0; r < 4; r++) fin[r] += g8[r][e] * ae[r];
  }

  int n = n0 + wn * 16 + lr;
  if (kz == 0) {  // fold gate-blended beta into the kz=0 partial
    float bv[8];
#pragma unroll
    for (int e = 0; e < 8; e++) bv[e] = beta[e * 512 + n];
#pragma unroll
    for (int r = 0; r < 4; r++) {
      float bs = 0.f;
#pragma unroll
      for (int e = 0; e < 8; e++) bs += g8[r][e] * bv[e];
      fin[r] += bs;
    }
  }
  if (ATOMIC) {
#pragma unroll
    for (int r = 0; r < 4; r++) {
      int m = m0 + wm * 16 + lk * 4 + r;
      atomicAdd(&Pout[(size_t)m * 512 + n], fin[r]);
    }
  } else {
    float* Po = Pout + (size_t)kz * Bq * Hq;
#pragma unroll
    for (int r = 0; r < 4; r++) {
      int m = m0 + wm * 16 + lk * 4 + r;
      Po[(size_t)m * 512 + n] = fin[r];
    }
  }
}

// === single persistent kernel (regular launch + software grid barrier) ======
// 512 blocks x 256 threads, 48 KB LDS, VGPR<=256 via launch bounds
// -> 2 blocks/CU co-resident on 256 CUs = all 512 blocks resident.
// Phase A: gating L0 (blk 0..255) || alpha0 cvt (blk 256..511, 8 chunks each)
// Phase B: gating L1 (0..255)     || alpha1 cvt (256..511)
// Phase C: softmax (0..127) || out-zero (128..383) || alpha2 cvt (384..511)
// Phase D/E/F: expert layers 1/2/3 (all 512 blocks as 16n x 16m x 2kz)
__global__ __launch_bounds__(256, 2) void fused_moe(
    const float* __restrict__ x, const float* __restrict__ gw0,
    const float* __restrict__ gb0, const float* __restrict__ gw1,
    const float* __restrict__ gb1, const float* __restrict__ gw2,
    const float* __restrict__ gb2, const float* __restrict__ alpha0,
    const float* __restrict__ beta0, const float* __restrict__ alpha1,
    const float* __restrict__ beta1, const float* __restrict__ alpha2,
    const float* __restrict__ beta2, unsigned short* __restrict__ a0b,
    unsigned short* __restrict__ a1b, unsigned short* __restrict__ a2b,
    unsigned short* __restrict__ G0b, unsigned short* __restrict__ G1b,
    float* __restrict__ gates, float* __restrict__ P1, float* __restrict__ P2,
    float* __restrict__ out, unsigned* __restrict__ bars) {
  __shared__ unsigned short sm[24 * 1024];  // 48 KB union (gating / expert)
  const int blk = blockIdx.x, tid = threadIdx.x;

  // Phase A: gating L0 (A,W VALU-staged from fp32) + alpha0 cvt rider
  if (blk < 256) {
    gating_tile<1>(blk, tid, sm, sm + 8192, nullptr, x, gw0, gb0, G0b);
  } else {
#pragma unroll
    for (int i = 0; i < 8; i++)
      cvt_chunk(alpha0, a0b, (blk - 256) * 8 + i, tid);
  }
  gsync(bars + 0);

  // Phase B: gating L1 (A from bf16 G0b) + alpha1 cvt rider
  if (blk < 256) {
    gating_tile<0>(blk, tid, sm, sm + 8192, G0b, nullptr, gw1, gb1, G1b);
  } else {
#pragma unroll
    for (int i = 0; i < 8; i++)
      cvt_chunk(alpha1, a1b, (blk - 256) * 8 + i, tid);
  }
  gsync(bars + 16);

  // Phase C: softmax || out-zero || alpha2 cvt
  if (blk < 128) {
    gate_softmax(blk, tid, G1b, gw2, gb2, gates);
  } else if (blk < 384) {
    ((float4*)out)[(blk - 128) * 256 + tid] = (float4){0.f, 0.f, 0.f, 0.f};
  } else {
#pragma unroll
    for (int i = 0; i < 16; i++)
      cvt_chunk(alpha2, a2b, (blk - 384) * 16 + i, tid);
  }
  gsync(bars + 32);

  // Phase D/E/F: expert layers
  expert_phase<1, 0, 0>(blk, tid, sm, x, nullptr, a0b, gates, beta0, P1);
  gsync(bars + 48);
  expert_phase<0, 1, 0>(blk, tid, sm, nullptr, P1, a1b, gates, beta1, P2);
  gsync(bars + 64);
  expert_phase<0, 1, 1>(blk, tid, sm, nullptr, P2, a2b, gates, beta2, out);
}

extern "C" void kernel_launch(void* const* d_in, const int* in_sizes, int n_in,
                              void* d_out, int out_size, void* d_ws,
                              size_t ws_size, hipStream_t stream) {
  const float* x = (const float*)d_in[0];
  const float* gw0 = (const float*)d_in[1];
  const float* gb0 = (const float*)d_in[2];
  const float* gw1 = (const float*)d_in[3];
  const float* gb1 = (const float*)d_in[4];
  const float* gw2 = (const float*)d_in[5];
  const float* gb2 = (const float*)d_in[6];
  const float* alpha0 = (const float*)d_in[7];
  const float* beta0 = (const float*)d_in[8];
  const float* alpha1 = (const float*)d_in[9];
  const float* beta1 = (const float*)d_in[10];
  const float* alpha2 = (const float*)d_in[11];
  const float* beta2 = (const float*)d_in[12];
  float* out = (float*)d_out;

  char* ws = (char*)d_ws;
  auto alloc = [&](size_t bytes) {
    char* p = ws;
    ws += (bytes + 255) & ~(size_t)255;
    return p;
  };
  unsigned short* a0b = (unsigned short*)alloc((size_t)Eq * Hq * Fq * 2);
  unsigned short* a1b = (unsigned short*)alloc((size_t)Eq * Hq * Hq * 2);
  unsigned short* a2b = (unsigned short*)alloc((size_t)Eq * Oq * Hq * 2);
  unsigned short* G0b = (unsigned short*)alloc((size_t)Bq * Hq * 2);
  unsigned short* G1b = (unsigned short*)alloc((size_t)Bq * Hq * 2);
  float* gates = (float*)alloc((size_t)Bq * Eq * 4);
  float* P1 = (float*)alloc((size_t)2 * Bq * Hq * 4);
  float* P2 = (float*)alloc((size_t)2 * Bq * Hq * 4);
  unsigned* bars = (unsigned*)alloc(512);  // 5 counters, 64 B apart

  // zero the barrier counters (stream-ordered; replayed per graph iteration)
  hipMemsetAsync(bars, 0, 512, stream);

  fused_moe<<<512, 256, 0, stream>>>(x, gw0, gb0, gw1, gb1, gw2, gb2, alpha0,
                                     beta0, alpha1, beta1, alpha2, beta2, a0b,
                                     a1b, a2b, G0b, G1b, gates, P1, P2, out,
                                     bars);
}

// Round 3
// 184.711 us; speedup vs baseline: 1.6518x; 1.6518x over previous
//
#include <hip/hip_runtime.h>
#include <hip/hip_bf16.h>
#include <math.h>

// Problem constants (B,F,H,E,O) = (512,512,512,8,512)
enum { Bq = 512, Fq = 512, Hq = 512, Eq = 8, Oq = 512 };
enum { KZN = 4, KB = 512 / KZN };  // expert-GEMM k-split: 4 x 128

typedef __attribute__((ext_vector_type(8))) short short8;
typedef __attribute__((ext_vector_type(4))) float floatx4;

static __device__ __forceinline__ unsigned short f2bf(float f) {
  unsigned u = __float_as_uint(f);
  u += 0x7fffu + ((u >> 16) & 1u);
  return (unsigned short)(u >> 16);
}
static __device__ __forceinline__ float bf2f(unsigned short h) {
  return __uint_as_float(((unsigned)h) << 16);
}
static __device__ __forceinline__ float elu1(float v) {
  return v > 0.f ? v : (__expf(v) - 1.f);
}

// async global->LDS 16B copy (wave-uniform LDS base + lane*16 scatter)
typedef __attribute__((address_space(1))) const unsigned int gu32;
typedef __attribute__((address_space(3))) unsigned int lu32;
static __device__ __forceinline__ void gld16(const unsigned short* g,
                                             unsigned short* l) {
  __builtin_amdgcn_global_load_lds((gu32*)g, (lu32*)l, 16, 0, 0);
}

// XOR swizzle on 16B chunks (fragment-read conflicts -> 2-way = free).
// Involution in q for fixed r; touches only low 3 bits of q.
static __device__ __forceinline__ int swz(int q, int r) {
  return (q & ~7) | ((q ^ r) & 7);
}

// one 256-thread block converts 256 float4 (1024 elems) fp32->bf16
static __device__ __forceinline__ void cvt_chunk(const float* __restrict__ src,
                                                 unsigned short* __restrict__ dst,
                                                 int chunk, int tid) {
  int j = chunk * 256 + tid;
  float4 v = ((const float4*)src)[j];
  ushort4 o;
  o.x = f2bf(v.x); o.y = f2bf(v.y); o.z = f2bf(v.z); o.w = f2bf(v.w);
  *(ushort4*)(dst + 4 * (size_t)j) = o;
}

// load 8 fp32 -> bf16x8
static __device__ __forceinline__ short8 cvt8(const float* __restrict__ p) {
  float4 v0 = *(const float4*)p, v1 = *(const float4*)(p + 4);
  short8 o;
  o[0] = (short)f2bf(v0.x); o[1] = (short)f2bf(v0.y);
  o[2] = (short)f2bf(v0.z); o[3] = (short)f2bf(v0.w);
  o[4] = (short)f2bf(v1.x); o[5] = (short)f2bf(v1.y);
  o[6] = (short)f2bf(v1.z); o[7] = (short)f2bf(v1.w);
  return o;
}

// === K1: whole gating chain in-block (blocks 0..15) + riders (16..815) ======
// Gating block: 32 samples through L0 -> L1 -> logits -> softmax with only
// __syncthreads(). LDS 64 KB: Ws dbuf 2x16KB (32x256 bf16 panels) + H1s 32KB.
// A-fragments live in registers (af[16] = 64 VGPR). Logits accumulate in
// p[4][8] registers during L1 epilogues (h2 never materialized).
// Riders: 800 blocks x 8 units; units = [a0 cvt|a1 cvt|a2 cvt|out zero].
__global__ __launch_bounds__(256, 2) void gate_all(
    const float* __restrict__ x, const float* __restrict__ gw0,
    const float* __restrict__ gb0, const float* __restrict__ gw1,
    const float* __restrict__ gb1, const float* __restrict__ gw2,
    const float* __restrict__ gb2,
    const float* __restrict__ alpha0, unsigned short* __restrict__ a0b,
    const float* __restrict__ alpha1, unsigned short* __restrict__ a1b,
    const float* __restrict__ alpha2, unsigned short* __restrict__ a2b,
    float* __restrict__ gates, float* __restrict__ outz) {
  __shared__ unsigned short sm[32768];  // 64 KB
  const int blk = blockIdx.x, tid = threadIdx.x;
  if (blk >= 16) {  // ---- riders: 8 contiguous units, never straddling type
    const int u0 = (blk - 16) * 8;
    if (u0 < 2048) {
#pragma unroll
      for (int i = 0; i < 8; i++) cvt_chunk(alpha0, a0b, u0 + i, tid);
    } else if (u0 < 4096) {
#pragma unroll
      for (int i = 0; i < 8; i++) cvt_chunk(alpha1, a1b, u0 - 2048 + i, tid);
    } else if (u0 < 6144) {
#pragma unroll
      for (int i = 0; i < 8; i++) cvt_chunk(alpha2, a2b, u0 - 4096 + i, tid);
    } else {
#pragma unroll
      for (int i = 0; i < 8; i++)
        ((float4*)outz)[(size_t)(u0 - 6144 + i) * 256 + tid] =
            (float4){0.f, 0.f, 0.f, 0.f};
    }
    return;
  }
  // ---- gating block ----
  unsigned short* Ws0 = sm;          // 16 KB (32 n-rows x 256 k bf16)
  unsigned short* Ws1 = sm + 8192;   // 16 KB
  unsigned short* H1s = sm + 16384;  // 32 KB (32 rows x 512 bf16, swizzled)
  const int wave = tid >> 6, lane = tid & 63;
  const int wm = wave >> 1, wn = wave & 1;
  const int lr = lane & 15, lk = lane >> 4;
  const int m0 = blk * 32;
  const int rA = wm * 16 + lr, rB = wn * 16 + lr;

  auto stage_w = [&](const float* __restrict__ gw, int nt, int kk,
                     unsigned short* W) {
#pragma unroll
    for (int i = 0; i < 4; i++) {
      int c = tid + i * 256;
      int r = c >> 5, q = c & 31;
      *(short8*)&W[(r * 32 + swz(q, r)) * 8] =
          cvt8(gw + (size_t)(nt * 32 + r) * 512 + kk * 256 + q * 8);
    }
  };

  // L0 A-fragments straight from global x: chunk (i*4+lk) of row m0+rA
  short8 af[16];
#pragma unroll
  for (int i = 0; i < 16; i++)
    af[i] = cvt8(x + (size_t)(m0 + rA) * 512 + (i * 4 + lk) * 8);
  stage_w(gw0, 0, 0, Ws0);

  float p[4][8];
#pragma unroll
  for (int r = 0; r < 4; r++)
#pragma unroll
    for (int e = 0; e < 8; e++) p[r][e] = 0.f;

  // ---- L0: h1 = elu(x @ gw0^T + gb0) -> H1s ----
  for (int nt = 0; nt < 16; ++nt) {
    floatx4 ac[4];
#pragma unroll
    for (int j = 0; j < 4; j++) ac[j] = (floatx4){0.f, 0.f, 0.f, 0.f};
    __syncthreads();  // Ws0(nt,0) staged by all; Ws1 free
    stage_w(gw0, nt, 1, Ws1);
#pragma unroll
    for (int s = 0; s < 8; s++) {
      short8 bv = *(const short8*)&Ws0[(rB * 32 + swz(s * 4 + lk, rB)) * 8];
      ac[s & 3] =
          __builtin_amdgcn_mfma_f32_16x16x32_bf16(af[s], bv, ac[s & 3], 0, 0, 0);
    }
    __syncthreads();  // Ws1(nt,1) staged; Ws0 reads done
    if (nt < 15) stage_w(gw0, nt + 1, 0, Ws0);
#pragma unroll
    for (int s = 0; s < 8; s++) {
      short8 bv = *(const short8*)&Ws1[(rB * 32 + swz(s * 4 + lk, rB)) * 8];
      ac[s & 3] = __builtin_amdgcn_mfma_f32_16x16x32_bf16(af[8 + s], bv,
                                                          ac[s & 3], 0, 0, 0);
    }
    floatx4 acc = (ac[0] + ac[1]) + (ac[2] + ac[3]);
    int col = nt * 32 + wn * 16 + lr;
    float b0 = gb0[col];
    // C/D layout (m89-verified): col = lane&15, row = (lane>>4)*4 + reg
#pragma unroll
    for (int r = 0; r < 4; r++) {
      int ml = wm * 16 + lk * 4 + r;
      H1s[(ml * 64 + swz(col >> 3, ml)) * 8 + (col & 7)] =
          f2bf(elu1(acc[r] + b0));
    }
  }

  stage_w(gw1, 0, 0, Ws0);  // safe: all waves past nt=15's mid-sync

  // ---- L1 + fused logit accumulation (h2 never stored) ----
  for (int nt = 0; nt < 16; ++nt) {
    floatx4 ac[4];
#pragma unroll
    for (int j = 0; j < 4; j++) ac[j] = (floatx4){0.f, 0.f, 0.f, 0.f};
    __syncthreads();  // Ws0(L1 nt,0) staged; H1s complete (first iter)
    if (nt == 0) {
#pragma unroll
      for (int i = 0; i < 16; i++)
        af[i] = *(const short8*)&H1s[(rA * 64 + swz(i * 4 + lk, rA)) * 8];
    }
    stage_w(gw1, nt, 1, Ws1);
#pragma unroll
    for (int s = 0; s < 8; s++) {
      short8 bv = *(const short8*)&Ws0[(rB * 32 + swz(s * 4 + lk, rB)) * 8];
      ac[s & 3] =
          __builtin_amdgcn_mfma_f32_16x16x32_bf16(af[s], bv, ac[s & 3], 0, 0, 0);
    }
    __syncthreads();
    if (nt < 15) stage_w(gw1, nt + 1, 0, Ws0);
#pragma unroll
    for (int s = 0; s < 8; s++) {
      short8 bv = *(const short8*)&Ws1[(rB * 32 + swz(s * 4 + lk, rB)) * 8];
      ac[s & 3] = __builtin_amdgcn_mfma_f32_16x16x32_bf16(af[8 + s], bv,
                                                          ac[s & 3], 0, 0, 0);
    }
    floatx4 acc = (ac[0] + ac[1]) + (ac[2] + ac[3]);
    int col = nt * 32 + wn * 16 + lr;
    float b1 = gb1[col];
    float vv[4];
#pragma unroll
    for (int r = 0; r < 4; r++) vv[r] = elu1(acc[r] + b1);
#pragma unroll
    for (int e = 0; e < 8; e++) {
      float ge = gw2[(size_t)e * 512 + col];
#pragma unroll
      for (int r = 0; r < 4; r++) p[r][e] += vv[r] * ge;
    }
  }

  // reduce logit partials over lr (16-lane groups share a row-quadrant)
#pragma unroll
  for (int off = 1; off <= 8; off <<= 1)
#pragma unroll
    for (int r = 0; r < 4; r++)
#pragma unroll
      for (int e = 0; e < 8; e++) p[r][e] += __shfl_xor(p[r][e], off);
  // scratch overlays Ws0 (last read was (15,0); all waves past mid-sync)
  float* scr = (float*)sm;  // [32 rows][2 col-halves][8 experts]
  if (lr == 0) {
#pragma unroll
    for (int r = 0; r < 4; r++)
#pragma unroll
      for (int e = 0; e < 8; e++)
        scr[(wm * 16 + lk * 4 + r) * 16 + wn * 8 + e] = p[r][e];
  }
  __syncthreads();
  if (tid < 32) {  // finisher: one lane per sample row
    int row = tid;
    float le[8], mx = -1e30f, ssum = 0.f;
#pragma unroll
    for (int e = 0; e < 8; e++) {
      le[e] = scr[row * 16 + e] + scr[row * 16 + 8 + e] + gb2[e];
      mx = fmaxf(mx, le[e]);
    }
#pragma unroll
    for (int e = 0; e < 8; e++) {
      le[e] = __expf(le[e] - mx);
      ssum += le[e];
    }
    float inv = 1.f / ssum;
#pragma unroll
    for (int e = 0; e < 8; e++)
      gates[(size_t)(m0 + row) * 8 + e] = le[e] * inv;
  }
}

// ---- expert GEMM: 32x32 tile, KB=128 k-slice, 8 experts/block, dbuf W ------
// grid (16 n, 16 m, 4 kz) = 1024 blocks, 24 KB LDS -> 4 blocks/CU (16 waves).
// A-fragments hoisted at e==0 (invariant over experts); FROMP sums KZN
// partials + elu on the fly; ATOMIC epilogue adds into pre-zeroed out.
template <int FROMX, int FROMP, int ATOMIC>
__global__ __launch_bounds__(256, 4) void expert_gemm(
    const float* __restrict__ Xf,           // [512,512] fp32 (FROMX)
    const float* __restrict__ Pin,          // [KZN][512][512] (FROMP)
    const unsigned short* __restrict__ Wb,  // [E*512,512] bf16 alpha bank
    const float* __restrict__ g,            // [512,8] gates
    const float* __restrict__ beta,         // [E*512] fp32
    float* __restrict__ Pout) {             // [KZN][512][512] or out
  __shared__ unsigned short As[32 * KB];      // 8 KB
  __shared__ unsigned short Wsb[2][32 * KB];  // 2 x 8 KB
  const int tid = threadIdx.x;
  const int wave = tid >> 6, lane = tid & 63;
  const int wm = wave >> 1, wn = wave & 1;
  const int lr = lane & 15, lk = lane >> 4;
  const int m0 = blockIdx.y * 32, n0 = blockIdx.x * 32;
  const int kz = blockIdx.z, kbeg = kz * KB;

  // stage A panel (32 x KB): 512 chunks, 2 per thread
  if (FROMP) {
#pragma unroll
    for (int i = 0; i < 2; i++) {
      int c = tid + i * 256;
      int r = c >> 4, q = c & 15;
      const float* pp = Pin + (size_t)(m0 + r) * 512 + kbeg + q * 8;
      float s[8] = {0.f, 0.f, 0.f, 0.f, 0.f, 0.f, 0.f, 0.f};
#pragma unroll
      for (int k = 0; k < KZN; k++) {
        const float* pk = pp + (size_t)k * (Bq * Hq);
        float4 va = *(const float4*)pk, vb = *(const float4*)(pk + 4);
        s[0] += va.x; s[1] += va.y; s[2] += va.z; s[3] += va.w;
        s[4] += vb.x; s[5] += vb.y; s[6] += vb.z; s[7] += vb.w;
      }
      short8 o;
#pragma unroll
      for (int j = 0; j < 8; j++) o[j] = (short)f2bf(elu1(s[j]));
      *(short8*)&As[(r * 16 + swz(q, r)) * 8] = o;
    }
  } else if (FROMX) {
#pragma unroll
    for (int i = 0; i < 2; i++) {
      int c = tid + i * 256;
      int r = c >> 4, q = c & 15;
      *(short8*)&As[(r * 16 + swz(q, r)) * 8] =
          cvt8(Xf + (size_t)(m0 + r) * 512 + kbeg + q * 8);
    }
  }
  // stage W panel for expert e into buffer b (gld16, pre-swizzled source)
  auto stageW = [&](int e, int b) {
    const unsigned short* Wp = Wb + ((size_t)e * 512 + n0) * 512 + kbeg;
#pragma unroll
    for (int i = 0; i < 2; i++) {
      int c = tid + i * 256;
      int r = c >> 4, ql = c & 15;
      gld16(&Wp[(size_t)r * 512 + swz(ql, r) * 8], &Wsb[b][(c & ~63) * 8]);
    }
  };
  stageW(0, 0);
  // gates for this lane's 4 output rows
  float g8[4][8];
#pragma unroll
  for (int r = 0; r < 4; r++) {
    int m = m0 + wm * 16 + lk * 4 + r;
    float4 ga = *(const float4*)&g[(size_t)m * 8];
    float4 gb = *(const float4*)&g[(size_t)m * 8 + 4];
    g8[r][0] = ga.x; g8[r][1] = ga.y; g8[r][2] = ga.z; g8[r][3] = ga.w;
    g8[r][4] = gb.x; g8[r][5] = gb.y; g8[r][6] = gb.z; g8[r][7] = gb.w;
  }

  const int rA = wm * 16 + lr, rB = wn * 16 + lr;
  short8 af[4];  // A fragments, hoisted once at e==0 (invariant over experts)
  floatx4 fin = {0.f, 0.f, 0.f, 0.f};
#pragma unroll
  for (int e = 0; e < 8; e++) {
    __syncthreads();                        // A + W[e] ready; fences reuse
    if (e < 7) stageW(e + 1, (e + 1) & 1);  // prefetch overlaps MFMA
    if (e == 0) {
#pragma unroll
      for (int s = 0; s < 4; s++)
        af[s] = *(const short8*)&As[(rA * 16 + swz(s * 4 + lk, rA)) * 8];
    }
    const unsigned short* wb = Wsb[e & 1];
    floatx4 c0 = {0.f, 0.f, 0.f, 0.f}, c1 = {0.f, 0.f, 0.f, 0.f};
#pragma unroll
    for (int s = 0; s < 4; s++) {
      short8 bv = *(const short8*)&wb[(rB * 16 + swz(s * 4 + lk, rB)) * 8];
      if (s & 1)
        c1 = __builtin_amdgcn_mfma_f32_16x16x32_bf16(af[s], bv, c1, 0, 0, 0);
      else
        c0 = __builtin_amdgcn_mfma_f32_16x16x32_bf16(af[s], bv, c0, 0, 0, 0);
    }
    floatx4 ae = c0 + c1;
#pragma unroll
    for (int r = 0; r < 4; r++) fin[r] += g8[r][e] * ae[r];
  }

  int n = n0 + wn * 16 + lr;
  if (kz == 0) {  // fold gate-blended beta into the kz=0 partial
    float bv[8];
#pragma unroll
    for (int e = 0; e < 8; e++) bv[e] = beta[e * 512 + n];
#pragma unroll
    for (int r = 0; r < 4; r++) {
      float bs = 0.f;
#pragma unroll
      for (int e = 0; e < 8; e++) bs += g8[r][e] * bv[e];
      fin[r] += bs;
    }
  }
  if (ATOMIC) {
#pragma unroll
    for (int r = 0; r < 4; r++) {
      int m = m0 + wm * 16 + lk * 4 + r;
      atomicAdd(&Pout[(size_t)m * 512 + n], fin[r]);
    }
  } else {
    float* Po = Pout + (size_t)kz * Bq * Hq;
#pragma unroll
    for (int r = 0; r < 4; r++) {
      int m = m0 + wm * 16 + lk * 4 + r;
      Po[(size_t)m * 512 + n] = fin[r];
    }
  }
}

extern "C" void kernel_launch(void* const* d_in, const int* in_sizes, int n_in,
                              void* d_out, int out_size, void* d_ws,
                              size_t ws_size, hipStream_t stream) {
  const float* x = (const float*)d_in[0];
  const float* gw0 = (const float*)d_in[1];
  const float* gb0 = (const float*)d_in[2];
  const float* gw1 = (const float*)d_in[3];
  const float* gb1 = (const float*)d_in[4];
  const float* gw2 = (const float*)d_in[5];
  const float* gb2 = (const float*)d_in[6];
  const float* alpha0 = (const float*)d_in[7];
  const float* beta0 = (const float*)d_in[8];
  const float* alpha1 = (const float*)d_in[9];
  const float* beta1 = (const float*)d_in[10];
  const float* alpha2 = (const float*)d_in[11];
  const float* beta2 = (const float*)d_in[12];
  float* out = (float*)d_out;

  char* ws = (char*)d_ws;
  auto alloc = [&](size_t bytes) {
    char* p = ws;
    ws += (bytes + 255) & ~(size_t)255;
    return p;
  };
  unsigned short* a0b = (unsigned short*)alloc((size_t)Eq * Hq * Fq * 2);
  unsigned short* a1b = (unsigned short*)alloc((size_t)Eq * Hq * Hq * 2);
  unsigned short* a2b = (unsigned short*)alloc((size_t)Eq * Oq * Hq * 2);
  float* gates = (float*)alloc((size_t)Bq * Eq * 4);
  float* P1 = (float*)alloc((size_t)KZN * Bq * Hq * 4);
  float* P2 = (float*)alloc((size_t)KZN * Bq * Hq * 4);

  // K1: full gating chain (16 blocks) + alpha cvt riders + out zero
  gate_all<<<816, 256, 0, stream>>>(x, gw0, gb0, gw1, gb1, gw2, gb2, alpha0,
                                    a0b, alpha1, a1b, alpha2, a2b, gates, out);
  // K2-K4: expert layers at 4 blocks/CU
  dim3 ge(16, 16, KZN);
  expert_gemm<1, 0, 0><<<ge, 256, 0, stream>>>(x, nullptr, a0b, gates, beta0,
                                               P1);
  expert_gemm<0, 1, 0><<<ge, 256, 0, stream>>>(nullptr, P1, a1b, gates, beta1,
                                               P2);
  expert_gemm<0, 1, 1><<<ge, 256, 0, stream>>>(nullptr, P2, a2b, gates, beta2,
                                               out);
}

// Round 4
// 135.896 us; speedup vs baseline: 2.2451x; 1.3592x over previous
//
#include <hip/hip_runtime.h>
#include <hip/hip_bf16.h>
#include <math.h>

// Problem constants (B,F,H,E,O) = (512,512,512,8,512)
enum { Bq = 512, Fq = 512, Hq = 512, Eq = 8, Oq = 512 };
enum { KZN = 4, KB = 128 };  // expert k-split: 4 x 128

typedef __attribute__((ext_vector_type(8))) short short8;
typedef __attribute__((ext_vector_type(4))) float floatx4;

static __device__ __forceinline__ unsigned short f2bf(float f) {
  unsigned u = __float_as_uint(f);
  u += 0x7fffu + ((u >> 16) & 1u);
  return (unsigned short)(u >> 16);
}
static __device__ __forceinline__ float elu1(float v) {
  return v > 0.f ? v : (__expf(v) - 1.f);
}

// async global->LDS 16B copy (wave-uniform LDS base + lane*16 scatter)
typedef __attribute__((address_space(1))) const unsigned int gu32;
typedef __attribute__((address_space(3))) unsigned int lu32;
static __device__ __forceinline__ void gld16(const unsigned short* g,
                                             unsigned short* l) {
  __builtin_amdgcn_global_load_lds((gu32*)g, (lu32*)l, 16, 0, 0);
}

// XOR swizzle on 16B chunks (involution in q for fixed r, low 3 bits only)
static __device__ __forceinline__ int swz(int q, int r) {
  return (q & ~7) | ((q ^ r) & 7);
}

// one 256-thread block converts 256 float4 (1024 elems) fp32->bf16
static __device__ __forceinline__ void cvt_chunk(const float* __restrict__ src,
                                                 unsigned short* __restrict__ dst,
                                                 int chunk, int tid) {
  int j = chunk * 256 + tid;
  float4 v = ((const float4*)src)[j];
  ushort4 o;
  o.x = f2bf(v.x); o.y = f2bf(v.y); o.z = f2bf(v.z); o.w = f2bf(v.w);
  *(ushort4*)(dst + 4 * (size_t)j) = o;
}

// load 8 fp32 -> bf16x8
static __device__ __forceinline__ short8 cvt8(const float* __restrict__ p) {
  float4 v0 = *(const float4*)p, v1 = *(const float4*)(p + 4);
  short8 o;
  o[0] = (short)f2bf(v0.x); o[1] = (short)f2bf(v0.y);
  o[2] = (short)f2bf(v0.z); o[3] = (short)f2bf(v0.w);
  o[4] = (short)f2bf(v1.x); o[5] = (short)f2bf(v1.y);
  o[6] = (short)f2bf(v1.z); o[7] = (short)f2bf(v1.w);
  return o;
}

// === K1: gating L0 (blocks 0..255) + riders ================================
// riders: a0 cvt (2048) | out zero (256) | P1 zero (256) | P2 zero (256)
//         | logits init to gb2 (1).  grid = 3073.
__global__ __launch_bounds__(256) void gate_l0(
    const float* __restrict__ x, const float* __restrict__ gw0,
    const float* __restrict__ gb0, unsigned short* __restrict__ G0b,
    const float* __restrict__ alpha0, unsigned short* __restrict__ a0b,
    float* __restrict__ outz, float* __restrict__ P1z,
    float* __restrict__ P2z, const float* __restrict__ gb2,
    float* __restrict__ logits) {
  const int blk = blockIdx.x, tid = threadIdx.x;
  if (blk >= 256) {
    int u = blk - 256;
    if (u < 2048) { cvt_chunk(alpha0, a0b, u, tid); return; }
    u -= 2048;
    if (u < 256) {
      ((float4*)outz)[(size_t)u * 256 + tid] = (float4){0.f, 0.f, 0.f, 0.f};
      return;
    }
    u -= 256;
    if (u < 256) {
      ((float4*)P1z)[(size_t)u * 256 + tid] = (float4){0.f, 0.f, 0.f, 0.f};
      return;
    }
    u -= 256;
    if (u < 256) {
      ((float4*)P2z)[(size_t)u * 256 + tid] = (float4){0.f, 0.f, 0.f, 0.f};
      return;
    }
#pragma unroll
    for (int i = 0; i < 16; i++) {
      int idx = tid * 16 + i;
      logits[idx] = gb2[idx & 7];
    }
    return;
  }
  // ---- 32x32 tile, full K=512, one barrier (R0-proven structure) ----
  __shared__ unsigned short As[32 * 512];
  __shared__ unsigned short Ws[32 * 512];
  const int wave = tid >> 6, lane = tid & 63;
  const int wm = wave >> 1, wn = wave & 1;
  const int lr = lane & 15, lk = lane >> 4;
  const int m0 = (blk >> 4) * 32, n0 = (blk & 15) * 32;
#pragma unroll
  for (int i = 0; i < 8; i++) {
    int c = tid + i * 256;
    int r = c >> 6, q = c & 63;
    *(short8*)&As[(r * 64 + swz(q, r)) * 8] =
        cvt8(x + (size_t)(m0 + r) * 512 + q * 8);
  }
#pragma unroll
  for (int i = 0; i < 8; i++) {
    int c = tid + i * 256;
    int r = c >> 6, q = c & 63;
    *(short8*)&Ws[(r * 64 + swz(q, r)) * 8] =
        cvt8(gw0 + (size_t)(n0 + r) * 512 + q * 8);
  }
  __syncthreads();
  const int rA = wm * 16 + lr, rB = wn * 16 + lr;
  floatx4 ac[4];
#pragma unroll
  for (int j = 0; j < 4; j++) ac[j] = (floatx4){0.f, 0.f, 0.f, 0.f};
#pragma unroll
  for (int t = 0; t < 4; t++) {
#pragma unroll
    for (int j = 0; j < 4; j++) {
      int q = j * 16 + t * 4 + lk;
      short8 av = *(const short8*)&As[(rA * 64 + swz(q, rA)) * 8];
      short8 bv = *(const short8*)&Ws[(rB * 64 + swz(q, rB)) * 8];
      ac[j] = __builtin_amdgcn_mfma_f32_16x16x32_bf16(av, bv, ac[j], 0, 0, 0);
    }
  }
  floatx4 acc = (ac[0] + ac[1]) + (ac[2] + ac[3]);
  int n = n0 + wn * 16 + lr;
  float bn = gb0[n];
  // C/D layout (m89-verified): col = lane&15, row = (lane>>4)*4 + reg
#pragma unroll
  for (int r = 0; r < 4; r++) {
    int m = m0 + wm * 16 + lk * 4 + r;
    G0b[(size_t)m * 512 + n] = f2bf(elu1(acc[r] + bn));
  }
}

// === K2: gating L1 + fused partial-logit atomics (blocks 0..255) ===========
// h2 never materialized: epilogue computes p[r][e] = sum_col elu(h2)*gw2[e][col]
// over this block's 32 cols, lane-reduces, atomicAdds into logits.
// riders: a1 cvt (256..2303) | a2 cvt (2304..4351).  grid = 4352.
__global__ __launch_bounds__(256) void gate_l1(
    const unsigned short* __restrict__ G0b, const float* __restrict__ gw1,
    const float* __restrict__ gb1, const float* __restrict__ gw2,
    float* __restrict__ logits, const float* __restrict__ alpha1,
    unsigned short* __restrict__ a1b, const float* __restrict__ alpha2,
    unsigned short* __restrict__ a2b) {
  const int blk = blockIdx.x, tid = threadIdx.x;
  if (blk >= 256) {
    int u = blk - 256;
    if (u < 2048) cvt_chunk(alpha1, a1b, u, tid);
    else cvt_chunk(alpha2, a2b, u - 2048, tid);
    return;
  }
  __shared__ unsigned short As[32 * 512];
  __shared__ unsigned short Ws[32 * 512];
  const int wave = tid >> 6, lane = tid & 63;
  const int wm = wave >> 1, wn = wave & 1;
  const int lr = lane & 15, lk = lane >> 4;
  const int m0 = (blk >> 4) * 32, n0 = (blk & 15) * 32;
#pragma unroll
  for (int i = 0; i < 8; i++) {
    int c = tid + i * 256;
    int r = c >> 6, q = c & 63;
    gld16(&G0b[(size_t)(m0 + r) * 512 + swz(q, r) * 8], &As[(c & ~63) * 8]);
  }
#pragma unroll
  for (int i = 0; i < 8; i++) {
    int c = tid + i * 256;
    int r = c >> 6, q = c & 63;
    *(short8*)&Ws[(r * 64 + swz(q, r)) * 8] =
        cvt8(gw1 + (size_t)(n0 + r) * 512 + q * 8);
  }
  __syncthreads();
  const int rA = wm * 16 + lr, rB = wn * 16 + lr;
  floatx4 ac[4];
#pragma unroll
  for (int j = 0; j < 4; j++) ac[j] = (floatx4){0.f, 0.f, 0.f, 0.f};
#pragma unroll
  for (int t = 0; t < 4; t++) {
#pragma unroll
    for (int j = 0; j < 4; j++) {
      int q = j * 16 + t * 4 + lk;
      short8 av = *(const short8*)&As[(rA * 64 + swz(q, rA)) * 8];
      short8 bv = *(const short8*)&Ws[(rB * 64 + swz(q, rB)) * 8];
      ac[j] = __builtin_amdgcn_mfma_f32_16x16x32_bf16(av, bv, ac[j], 0, 0, 0);
    }
  }
  floatx4 acc = (ac[0] + ac[1]) + (ac[2] + ac[3]);
  int col = n0 + wn * 16 + lr;
  float b1 = gb1[col];
  float pl[4][8];
  {
    float vv[4];
#pragma unroll
    for (int r = 0; r < 4; r++) vv[r] = elu1(acc[r] + b1);
#pragma unroll
    for (int e = 0; e < 8; e++) {
      float ge = gw2[(size_t)e * 512 + col];
#pragma unroll
      for (int r = 0; r < 4; r++) pl[r][e] = vv[r] * ge;
    }
  }
  // reduce over the 16 lr lanes (lane = lk*16+lr; xor<=8 flips only lr bits)
#pragma unroll
  for (int o = 1; o <= 8; o <<= 1)
#pragma unroll
    for (int r = 0; r < 4; r++)
#pragma unroll
      for (int e = 0; e < 8; e++) pl[r][e] += __shfl_xor(pl[r][e], o);
  __syncthreads();  // all waves done reading Ws -> safe to overlay
  float* scr = (float*)Ws;  // [2 wn][32 row][8 e]
  if (lr == 0) {
#pragma unroll
    for (int r = 0; r < 4; r++)
#pragma unroll
      for (int e = 0; e < 8; e++)
        scr[wn * 256 + (wm * 16 + lk * 4 + r) * 8 + e] = pl[r][e];
  }
  __syncthreads();
  {
    int row = tid >> 3, e = tid & 7;
    float v = scr[row * 8 + e] + scr[256 + row * 8 + e];
    atomicAdd(&logits[(size_t)(m0 + row) * 8 + e], v);
  }
}

// === expert GEMM: 32x32 tile, 8 experts, dbuf W, atomic k-accumulate =======
// 1D grid 1024, XCD-grouped decode: the 16 m-blocks sharing a (n0,kz) W-panel
// land on one XCD (idx = xcd + 8*(slot*16+m)) -> W re-reads are L2-local.
// Inline softmax from logits (gb2 pre-folded). FROMX: A=x (no elu);
// else A = combined P partials, elu at staging. Always atomicAdd epilogue.
template <int FROMX>
__global__ __launch_bounds__(256, 4) void expert_gemm(
    const float* __restrict__ Af,           // x or P (combined fp32)
    const unsigned short* __restrict__ Wb,  // [E*512,512] bf16 alpha bank
    const float* __restrict__ logits,       // [512,8]
    const float* __restrict__ beta,         // [E*512] fp32
    float* __restrict__ Pout) {             // zeroed accumulation target
  __shared__ unsigned short As[32 * KB];      // 8 KB
  __shared__ unsigned short Wsb[2][32 * KB];  // 2 x 8 KB
  __shared__ float sgate[32 * 8];             // 1 KB
  const int tid = threadIdx.x;
  const int idx = blockIdx.x;
  const int mm = (idx >> 3) & 15, slot = idx >> 7;
  const int grp = slot * 8 + (idx & 7);  // (n,kz) group 0..63, XCD-local
  const int n0 = (grp >> 2) * 32, kz = grp & 3, kbeg = kz * KB;
  const int m0 = mm * 32;
  const int wave = tid >> 6, lane = tid & 63;
  const int wm = wave >> 1, wn = wave & 1;
  const int lr = lane & 15, lk = lane >> 4;

  // stage A panel (32 x 128): 512 chunks, 2 per thread
#pragma unroll
  for (int i = 0; i < 2; i++) {
    int c = tid + i * 256;
    int r = c >> 4, q = c & 15;
    const float* pp = Af + (size_t)(m0 + r) * 512 + kbeg + q * 8;
    float4 a = *(const float4*)pp, b = *(const float4*)(pp + 4);
    float v[8] = {a.x, a.y, a.z, a.w, b.x, b.y, b.z, b.w};
    short8 o;
#pragma unroll
    for (int j = 0; j < 8; j++)
      o[j] = (short)f2bf(FROMX ? v[j] : elu1(v[j]));
    *(short8*)&As[(r * 16 + swz(q, r)) * 8] = o;
  }
  auto stageW = [&](int e, int b) {
    const unsigned short* Wp = Wb + ((size_t)e * 512 + n0) * 512 + kbeg;
#pragma unroll
    for (int i = 0; i < 2; i++) {
      int c = tid + i * 256;
      int r = c >> 4, ql = c & 15;
      gld16(&Wp[(size_t)r * 512 + swz(ql, r) * 8], &Wsb[b][(c & ~63) * 8]);
    }
  };
  stageW(0, 0);
  // inline softmax: thread t -> (row=t>>3, e=t&7); 8-lane shfl group
  {
    int row = tid >> 3, e = tid & 7;
    float le = logits[(size_t)(m0 + row) * 8 + e];
    float mx = le;
#pragma unroll
    for (int o = 1; o <= 4; o <<= 1) mx = fmaxf(mx, __shfl_xor(mx, o));
    float ex = __expf(le - mx), sum = ex;
#pragma unroll
    for (int o = 1; o <= 4; o <<= 1) sum += __shfl_xor(sum, o);
    sgate[row * 8 + e] = ex / sum;
  }

  const int rA = wm * 16 + lr, rB = wn * 16 + lr;
  short8 af[4];
  float g8[4][8];
  floatx4 fin = {0.f, 0.f, 0.f, 0.f};
#pragma unroll
  for (int e = 0; e < 8; e++) {
    __syncthreads();                        // A + W[e] + sgate ready
    if (e < 7) stageW(e + 1, (e + 1) & 1);  // prefetch overlaps MFMA
    if (e == 0) {
#pragma unroll
      for (int s = 0; s < 4; s++)
        af[s] = *(const short8*)&As[(rA * 16 + swz(s * 4 + lk, rA)) * 8];
#pragma unroll
      for (int r = 0; r < 4; r++)
#pragma unroll
        for (int q = 0; q < 8; q++)
          g8[r][q] = sgate[(wm * 16 + lk * 4 + r) * 8 + q];
    }
    const unsigned short* wb = Wsb[e & 1];
    floatx4 c0 = {0.f, 0.f, 0.f, 0.f}, c1 = {0.f, 0.f, 0.f, 0.f};
#pragma unroll
    for (int s = 0; s < 4; s++) {
      short8 bv = *(const short8*)&wb[(rB * 16 + swz(s * 4 + lk, rB)) * 8];
      if (s & 1)
        c1 = __builtin_amdgcn_mfma_f32_16x16x32_bf16(af[s], bv, c1, 0, 0, 0);
      else
        c0 = __builtin_amdgcn_mfma_f32_16x16x32_bf16(af[s], bv, c0, 0, 0, 0);
    }
    floatx4 ae = c0 + c1;
#pragma unroll
    for (int r = 0; r < 4; r++) fin[r] += g8[r][e] * ae[r];
  }

  int n = n0 + wn * 16 + lr;
  if (kz == 0) {  // fold gate-blended beta once
    float bv[8];
#pragma unroll
    for (int e = 0; e < 8; e++) bv[e] = beta[e * 512 + n];
#pragma unroll
    for (int r = 0; r < 4; r++) {
      float bs = 0.f;
#pragma unroll
      for (int e = 0; e < 8; e++) bs += g8[r][e] * bv[e];
      fin[r] += bs;
    }
  }
#pragma unroll
  for (int r = 0; r < 4; r++) {
    int m = m0 + wm * 16 + lk * 4 + r;
    atomicAdd(&Pout[(size_t)m * 512 + n], fin[r]);
  }
}

extern "C" void kernel_launch(void* const* d_in, const int* in_sizes, int n_in,
                              void* d_out, int out_size, void* d_ws,
                              size_t ws_size, hipStream_t stream) {
  const float* x = (const float*)d_in[0];
  const float* gw0 = (const float*)d_in[1];
  const float* gb0 = (const float*)d_in[2];
  const float* gw1 = (const float*)d_in[3];
  const float* gb1 = (const float*)d_in[4];
  const float* gw2 = (const float*)d_in[5];
  const float* gb2 = (const float*)d_in[6];
  const float* alpha0 = (const float*)d_in[7];
  const float* beta0 = (const float*)d_in[8];
  const float* alpha1 = (const float*)d_in[9];
  const float* beta1 = (const float*)d_in[10];
  const float* alpha2 = (const float*)d_in[11];
  const float* beta2 = (const float*)d_in[12];
  float* out = (float*)d_out;

  char* ws = (char*)d_ws;
  auto alloc = [&](size_t bytes) {
    char* p = ws;
    ws += (bytes + 255) & ~(size_t)255;
    return p;
  };
  unsigned short* a0b = (unsigned short*)alloc((size_t)Eq * Hq * Fq * 2);
  unsigned short* a1b = (unsigned short*)alloc((size_t)Eq * Hq * Hq * 2);
  unsigned short* a2b = (unsigned short*)alloc((size_t)Eq * Oq * Hq * 2);
  unsigned short* G0b = (unsigned short*)alloc((size_t)Bq * Hq * 2);
  float* logits = (float*)alloc((size_t)Bq * Eq * 4);
  float* P1 = (float*)alloc((size_t)Bq * Hq * 4);
  float* P2 = (float*)alloc((size_t)Bq * Hq * 4);

  // K1: gating L0 + a0 cvt + zero(out,P1,P2) + logits=gb2
  gate_l0<<<3073, 256, 0, stream>>>(x, gw0, gb0, G0b, alpha0, a0b, out, P1,
                                    P2, gb2, logits);
  // K2: gating L1 -> partial logits; a1 + a2 cvt riders
  gate_l1<<<4352, 256, 0, stream>>>(G0b, gw1, gb1, gw2, logits, alpha1, a1b,
                                    alpha2, a2b);
  // K3-K5: expert layers (inline softmax; atomic k-accumulate)
  expert_gemm<1><<<1024, 256, 0, stream>>>(x, a0b, logits, beta0, P1);
  expert_gemm<0><<<1024, 256, 0, stream>>>(P1, a1b, logits, beta1, P2);
  expert_gemm<0><<<1024, 256, 0, stream>>>(P2, a2b, logits, beta2, out);
}

// Round 5
// 135.273 us; speedup vs baseline: 2.2555x; 1.0046x over previous
//
#include <hip/hip_runtime.h>
#include <hip/hip_bf16.h>
#include <math.h>

// Problem constants (B,F,H,E,O) = (512,512,512,8,512)
enum { Bq = 512, Fq = 512, Hq = 512, Eq = 8, Oq = 512 };
enum { KZN = 4, KB = 128 };  // expert k-split: 4 x 128

typedef __attribute__((ext_vector_type(8))) short short8;
typedef __attribute__((ext_vector_type(4))) float floatx4;

static __device__ __forceinline__ unsigned short f2bf(float f) {
  unsigned u = __float_as_uint(f);
  u += 0x7fffu + ((u >> 16) & 1u);
  return (unsigned short)(u >> 16);
}
static __device__ __forceinline__ float elu1(float v) {
  return v > 0.f ? v : (__expf(v) - 1.f);
}

// async global->LDS 16B copy (wave-uniform LDS base + lane*16 scatter)
typedef __attribute__((address_space(1))) const unsigned int gu32;
typedef __attribute__((address_space(3))) unsigned int lu32;
static __device__ __forceinline__ void gld16(const unsigned short* g,
                                             unsigned short* l) {
  __builtin_amdgcn_global_load_lds((gu32*)g, (lu32*)l, 16, 0, 0);
}

// XOR swizzle on 16B chunks (involution in q for fixed r, low 3 bits only)
static __device__ __forceinline__ int swz(int q, int r) {
  return (q & ~7) | ((q ^ r) & 7);
}

// load 8 fp32 -> bf16x8
static __device__ __forceinline__ short8 cvt8(const float* __restrict__ p) {
  float4 v0 = *(const float4*)p, v1 = *(const float4*)(p + 4);
  short8 o;
  o[0] = (short)f2bf(v0.x); o[1] = (short)f2bf(v0.y);
  o[2] = (short)f2bf(v0.z); o[3] = (short)f2bf(v0.w);
  o[4] = (short)f2bf(v1.x); o[5] = (short)f2bf(v1.y);
  o[6] = (short)f2bf(v1.z); o[7] = (short)f2bf(v1.w);
  return o;
}

// === K1: gating L0 (blocks 0..255) + zero riders ============================
// riders: out zero (256) | P1 zero (256) | P2 zero (256) | logits=gb2 (1).
// grid = 1025.  No alpha cvt passes anymore (experts stage fp32 directly).
__global__ __launch_bounds__(256) void gate_l0(
    const float* __restrict__ x, const float* __restrict__ gw0,
    const float* __restrict__ gb0, unsigned short* __restrict__ G0b,
    float* __restrict__ outz, float* __restrict__ P1z,
    float* __restrict__ P2z, const float* __restrict__ gb2,
    float* __restrict__ logits) {
  const int blk = blockIdx.x, tid = threadIdx.x;
  if (blk >= 256) {
    int u = blk - 256;
    if (u < 256) {
      ((float4*)outz)[(size_t)u * 256 + tid] = (float4){0.f, 0.f, 0.f, 0.f};
      return;
    }
    u -= 256;
    if (u < 256) {
      ((float4*)P1z)[(size_t)u * 256 + tid] = (float4){0.f, 0.f, 0.f, 0.f};
      return;
    }
    u -= 256;
    if (u < 256) {
      ((float4*)P2z)[(size_t)u * 256 + tid] = (float4){0.f, 0.f, 0.f, 0.f};
      return;
    }
#pragma unroll
    for (int i = 0; i < 16; i++) {
      int idx = tid * 16 + i;
      logits[idx] = gb2[idx & 7];
    }
    return;
  }
  // ---- 32x32 tile, full K=512, one barrier (R0-proven structure) ----
  __shared__ unsigned short As[32 * 512];
  __shared__ unsigned short Ws[32 * 512];
  const int wave = tid >> 6, lane = tid & 63;
  const int wm = wave >> 1, wn = wave & 1;
  const int lr = lane & 15, lk = lane >> 4;
  const int m0 = (blk >> 4) * 32, n0 = (blk & 15) * 32;
#pragma unroll
  for (int i = 0; i < 8; i++) {
    int c = tid + i * 256;
    int r = c >> 6, q = c & 63;
    *(short8*)&As[(r * 64 + swz(q, r)) * 8] =
        cvt8(x + (size_t)(m0 + r) * 512 + q * 8);
  }
#pragma unroll
  for (int i = 0; i < 8; i++) {
    int c = tid + i * 256;
    int r = c >> 6, q = c & 63;
    *(short8*)&Ws[(r * 64 + swz(q, r)) * 8] =
        cvt8(gw0 + (size_t)(n0 + r) * 512 + q * 8);
  }
  __syncthreads();
  const int rA = wm * 16 + lr, rB = wn * 16 + lr;
  floatx4 ac[4];
#pragma unroll
  for (int j = 0; j < 4; j++) ac[j] = (floatx4){0.f, 0.f, 0.f, 0.f};
#pragma unroll
  for (int t = 0; t < 4; t++) {
#pragma unroll
    for (int j = 0; j < 4; j++) {
      int q = j * 16 + t * 4 + lk;
      short8 av = *(const short8*)&As[(rA * 64 + swz(q, rA)) * 8];
      short8 bv = *(const short8*)&Ws[(rB * 64 + swz(q, rB)) * 8];
      ac[j] = __builtin_amdgcn_mfma_f32_16x16x32_bf16(av, bv, ac[j], 0, 0, 0);
    }
  }
  floatx4 acc = (ac[0] + ac[1]) + (ac[2] + ac[3]);
  int n = n0 + wn * 16 + lr;
  float bn = gb0[n];
  // C/D layout (m89-verified): col = lane&15, row = (lane>>4)*4 + reg
#pragma unroll
  for (int r = 0; r < 4; r++) {
    int m = m0 + wm * 16 + lk * 4 + r;
    G0b[(size_t)m * 512 + n] = f2bf(elu1(acc[r] + bn));
  }
}

// === K2: gating L1 + fused partial-logit atomics (256 blocks, no riders) ====
// h2 never materialized: epilogue computes p[r][e] = sum_col elu(h2)*gw2[e][col]
// over this block's 32 cols, lane-reduces, atomicAdds into logits.
__global__ __launch_bounds__(256) void gate_l1(
    const unsigned short* __restrict__ G0b, const float* __restrict__ gw1,
    const float* __restrict__ gb1, const float* __restrict__ gw2,
    float* __restrict__ logits) {
  const int blk = blockIdx.x, tid = threadIdx.x;
  __shared__ unsigned short As[32 * 512];
  __shared__ unsigned short Ws[32 * 512];
  const int wave = tid >> 6, lane = tid & 63;
  const int wm = wave >> 1, wn = wave & 1;
  const int lr = lane & 15, lk = lane >> 4;
  const int m0 = (blk >> 4) * 32, n0 = (blk & 15) * 32;
#pragma unroll
  for (int i = 0; i < 8; i++) {
    int c = tid + i * 256;
    int r = c >> 6, q = c & 63;
    gld16(&G0b[(size_t)(m0 + r) * 512 + swz(q, r) * 8], &As[(c & ~63) * 8]);
  }
#pragma unroll
  for (int i = 0; i < 8; i++) {
    int c = tid + i * 256;
    int r = c >> 6, q = c & 63;
    *(short8*)&Ws[(r * 64 + swz(q, r)) * 8] =
        cvt8(gw1 + (size_t)(n0 + r) * 512 + q * 8);
  }
  __syncthreads();
  const int rA = wm * 16 + lr, rB = wn * 16 + lr;
  floatx4 ac[4];
#pragma unroll
  for (int j = 0; j < 4; j++) ac[j] = (floatx4){0.f, 0.f, 0.f, 0.f};
#pragma unroll
  for (int t = 0; t < 4; t++) {
#pragma unroll
    for (int j = 0; j < 4; j++) {
      int q = j * 16 + t * 4 + lk;
      short8 av = *(const short8*)&As[(rA * 64 + swz(q, rA)) * 8];
      short8 bv = *(const short8*)&Ws[(rB * 64 + swz(q, rB)) * 8];
      ac[j] = __builtin_amdgcn_mfma_f32_16x16x32_bf16(av, bv, ac[j], 0, 0, 0);
    }
  }
  floatx4 acc = (ac[0] + ac[1]) + (ac[2] + ac[3]);
  int col = n0 + wn * 16 + lr;
  float b1 = gb1[col];
  float pl[4][8];
  {
    float vv[4];
#pragma unroll
    for (int r = 0; r < 4; r++) vv[r] = elu1(acc[r] + b1);
#pragma unroll
    for (int e = 0; e < 8; e++) {
      float ge = gw2[(size_t)e * 512 + col];
#pragma unroll
      for (int r = 0; r < 4; r++) pl[r][e] = vv[r] * ge;
    }
  }
  // reduce over the 16 lr lanes (lane = lk*16+lr; xor<=8 flips only lr bits)
#pragma unroll
  for (int o = 1; o <= 8; o <<= 1)
#pragma unroll
    for (int r = 0; r < 4; r++)
#pragma unroll
      for (int e = 0; e < 8; e++) pl[r][e] += __shfl_xor(pl[r][e], o);
  __syncthreads();  // all waves done reading Ws -> safe to overlay
  float* scr = (float*)Ws;  // [2 wn][32 row][8 e]
  if (lr == 0) {
#pragma unroll
    for (int r = 0; r < 4; r++)
#pragma unroll
      for (int e = 0; e < 8; e++)
        scr[wn * 256 + (wm * 16 + lk * 4 + r) * 8 + e] = pl[r][e];
  }
  __syncthreads();
  {
    int row = tid >> 3, e = tid & 7;
    float v = scr[row * 8 + e] + scr[256 + row * 8 + e];
    atomicAdd(&logits[(size_t)(m0 + row) * 8 + e], v);
  }
}

// === expert GEMM: 32x32 tile, 8 experts, dbuf W from fp32, atomic k-accum ===
// 1D grid 1024, XCD-grouped decode: the 16 m-blocks sharing a (n0,kz) W-panel
// land on one XCD (idx = slot*128 + mm*8 + xcd) -> per-XCD unique fp32 W per
// layer = 1 MB -> L2-resident; 16x re-reads are XCD-local.
// W staged straight from fp32 alpha via VALU cvt (no bf16 bank pass at all).
// Inline softmax from logits (gb2 pre-folded). FROMX: A=x (no elu);
// else A = combined P partials, elu at staging. Always atomicAdd epilogue.
template <int FROMX>
__global__ __launch_bounds__(256, 4) void expert_gemm(
    const float* __restrict__ Af,       // x or P (combined fp32)
    const float* __restrict__ Wf,       // [E*512,512] fp32 alpha
    const float* __restrict__ logits,   // [512,8]
    const float* __restrict__ beta,     // [E*512] fp32
    float* __restrict__ Pout) {         // zeroed accumulation target
  __shared__ unsigned short As[32 * KB];      // 8 KB
  __shared__ unsigned short Wsb[2][32 * KB];  // 2 x 8 KB
  __shared__ float sgate[32 * 8];             // 1 KB
  const int tid = threadIdx.x;
  const int idx = blockIdx.x;
  const int mm = (idx >> 3) & 15, slot = idx >> 7;
  const int grp = slot * 8 + (idx & 7);  // (n,kz) group 0..63, XCD-local
  const int n0 = (grp >> 2) * 32, kz = grp & 3, kbeg = kz * KB;
  const int m0 = mm * 32;
  const int wave = tid >> 6, lane = tid & 63;
  const int wm = wave >> 1, wn = wave & 1;
  const int lr = lane & 15, lk = lane >> 4;

  // stage A panel (32 x 128): 512 chunks, 2 per thread
#pragma unroll
  for (int i = 0; i < 2; i++) {
    int c = tid + i * 256;
    int r = c >> 4, q = c & 15;
    const float* pp = Af + (size_t)(m0 + r) * 512 + kbeg + q * 8;
    float4 a = *(const float4*)pp, b = *(const float4*)(pp + 4);
    float v[8] = {a.x, a.y, a.z, a.w, b.x, b.y, b.z, b.w};
    short8 o;
#pragma unroll
    for (int j = 0; j < 8; j++)
      o[j] = (short)f2bf(FROMX ? v[j] : elu1(v[j]));
    *(short8*)&As[(r * 16 + swz(q, r)) * 8] = o;
  }
  // stage W panel for expert e into buffer b: fp32 -> bf16 VALU cvt
  auto stageW = [&](int e, int b) {
    const float* Wp = Wf + ((size_t)e * 512 + n0) * 512 + kbeg;
#pragma unroll
    for (int i = 0; i < 2; i++) {
      int c = tid + i * 256;
      int r = c >> 4, q = c & 15;
      *(short8*)&Wsb[b][(r * 16 + swz(q, r)) * 8] =
          cvt8(Wp + (size_t)r * 512 + q * 8);
    }
  };
  stageW(0, 0);
  // inline softmax: thread t -> (row=t>>3, e=t&7); 8-lane shfl group
  {
    int row = tid >> 3, e = tid & 7;
    float le = logits[(size_t)(m0 + row) * 8 + e];
    float mx = le;
#pragma unroll
    for (int o = 1; o <= 4; o <<= 1) mx = fmaxf(mx, __shfl_xor(mx, o));
    float ex = __expf(le - mx), sum = ex;
#pragma unroll
    for (int o = 1; o <= 4; o <<= 1) sum += __shfl_xor(sum, o);
    sgate[row * 8 + e] = ex / sum;
  }

  const int rA = wm * 16 + lr, rB = wn * 16 + lr;
  short8 af[4];
  float g8[4][8];
  floatx4 fin = {0.f, 0.f, 0.f, 0.f};
#pragma unroll
  for (int e = 0; e < 8; e++) {
    __syncthreads();                        // A + W[e] + sgate ready
    if (e < 7) stageW(e + 1, (e + 1) & 1);  // prefetch overlaps MFMA
    if (e == 0) {
#pragma unroll
      for (int s = 0; s < 4; s++)
        af[s] = *(const short8*)&As[(rA * 16 + swz(s * 4 + lk, rA)) * 8];
#pragma unroll
      for (int r = 0; r < 4; r++)
#pragma unroll
        for (int q = 0; q < 8; q++)
          g8[r][q] = sgate[(wm * 16 + lk * 4 + r) * 8 + q];
    }
    const unsigned short* wb = Wsb[e & 1];
    floatx4 c0 = {0.f, 0.f, 0.f, 0.f}, c1 = {0.f, 0.f, 0.f, 0.f};
#pragma unroll
    for (int s = 0; s < 4; s++) {
      short8 bv = *(const short8*)&wb[(rB * 16 + swz(s * 4 + lk, rB)) * 8];
      if (s & 1)
        c1 = __builtin_amdgcn_mfma_f32_16x16x32_bf16(af[s], bv, c1, 0, 0, 0);
      else
        c0 = __builtin_amdgcn_mfma_f32_16x16x32_bf16(af[s], bv, c0, 0, 0, 0);
    }
    floatx4 ae = c0 + c1;
#pragma unroll
    for (int r = 0; r < 4; r++) fin[r] += g8[r][e] * ae[r];
  }

  int n = n0 + wn * 16 + lr;
  if (kz == 0) {  // fold gate-blended beta once
    float bv[8];
#pragma unroll
    for (int e = 0; e < 8; e++) bv[e] = beta[e * 512 + n];
#pragma unroll
    for (int r = 0; r < 4; r++) {
      float bs = 0.f;
#pragma unroll
      for (int e = 0; e < 8; e++) bs += g8[r][e] * bv[e];
      fin[r] += bs;
    }
  }
#pragma unroll
  for (int r = 0; r < 4; r++) {
    int m = m0 + wm * 16 + lk * 4 + r;
    atomicAdd(&Pout[(size_t)m * 512 + n], fin[r]);
  }
}

extern "C" void kernel_launch(void* const* d_in, const int* in_sizes, int n_in,
                              void* d_out, int out_size, void* d_ws,
                              size_t ws_size, hipStream_t stream) {
  const float* x = (const float*)d_in[0];
  const float* gw0 = (const float*)d_in[1];
  const float* gb0 = (const float*)d_in[2];
  const float* gw1 = (const float*)d_in[3];
  const float* gb1 = (const float*)d_in[4];
  const float* gw2 = (const float*)d_in[5];
  const float* gb2 = (const float*)d_in[6];
  const float* alpha0 = (const float*)d_in[7];
  const float* beta0 = (const float*)d_in[8];
  const float* alpha1 = (const float*)d_in[9];
  const float* beta1 = (const float*)d_in[10];
  const float* alpha2 = (const float*)d_in[11];
  const float* beta2 = (const float*)d_in[12];
  float* out = (float*)d_out;

  char* ws = (char*)d_ws;
  auto alloc = [&](size_t bytes) {
    char* p = ws;
    ws += (bytes + 255) & ~(size_t)255;
    return p;
  };
  unsigned short* G0b = (unsigned short*)alloc((size_t)Bq * Hq * 2);
  float* logits = (float*)alloc((size_t)Bq * Eq * 4);
  float* P1 = (float*)alloc((size_t)Bq * Hq * 4);
  float* P2 = (float*)alloc((size_t)Bq * Hq * 4);

  // K1: gating L0 + zero(out,P1,P2) + logits=gb2
  gate_l0<<<1025, 256, 0, stream>>>(x, gw0, gb0, G0b, out, P1, P2, gb2,
                                    logits);
  // K2: gating L1 -> partial logits
  gate_l1<<<256, 256, 0, stream>>>(G0b, gw1, gb1, gw2, logits);
  // K3-K5: expert layers (W staged from fp32; inline softmax; atomic k-accum)
  expert_gemm<1><<<1024, 256, 0, stream>>>(x, alpha0, logits, beta0, P1);
  expert_gemm<0><<<1024, 256, 0, stream>>>(P1, alpha1, logits, beta1, P2);
  expert_gemm<0><<<1024, 256, 0, stream>>>(P2, alpha2, logits, beta2, out);
}